// Round 14
// baseline (388.254 us; speedup 1.0000x reference)
//
#include <hip/hip_runtime.h>
#include <hip/hip_bf16.h>

typedef __attribute__((ext_vector_type(8))) __bf16 bf16x8;
typedef __attribute__((ext_vector_type(4))) float f32x4;
typedef unsigned short u16;

#define DEV static __device__ __forceinline__

#define BAR() asm volatile("s_barrier" ::: "memory")
#define LGKM0() asm volatile("s_waitcnt lgkmcnt(0)" ::: "memory")
#define VMCNT6() asm volatile("s_waitcnt vmcnt(6)" ::: "memory")
#define VMCNT3() asm volatile("s_waitcnt vmcnt(3)" ::: "memory")
#define VMCNT0() asm volatile("s_waitcnt vmcnt(0)" ::: "memory")

DEV void load_lds16(const void* g, void* l) {
  __builtin_amdgcn_global_load_lds(
      (const __attribute__((address_space(1))) unsigned int*)g,
      (__attribute__((address_space(3))) unsigned int*)l, 16, 0, 0);
}

DEV u16 bf16bits(float v) {
  __hip_bfloat16 h = __float2bfloat16(v);
  return __builtin_bit_cast(u16, h);
}

// BK=64 swizzled frag read (rows 128B; conflict-free, key l&7)
DEV bf16x8 rdfrag(const u16* region, int row, int ks, int l) {
  const int cb = (((ks << 6) | ((l >> 4) << 4)) ^ ((l & 7) << 4));
  return *(const bf16x8*)((const char*)region + row * 128 + cb);
}

// BK=32 swizzled frag read (rows 64B; key (row>>1)&3, verified 0-conflict)
DEV bf16x8 rdfrag32(const u16* region, int row, int l) {
  const int cb = (((l >> 4) ^ ((row >> 1) & 3)) << 4);
  return *(const bf16x8*)((const char*)region + row * 64 + cb);
}

struct OffN { unsigned long long a[12], b[12], c[12]; };

enum { G128_SC = 0, G128_PV = 1, G128_WO = 2, G128_LEAKY = 3 };

// ---------------- QKV 256x256 deep-pipelined GEMM (8 waves, BK=64) -----------
__global__ __launch_bounds__(512, 1) void k_qkv256(
    const u16* __restrict__ A, const u16* __restrict__ B,
    const float* __restrict__ bias, u16* __restrict__ C, u16* __restrict__ Vt)
{
  int flat = blockIdx.y * 27 + blockIdx.x;       // 864 = 8 * 108, bijective
  flat = (flat & 7) * 108 + (flat >> 3);
  const int n0 = (flat % 27) * 256, m0 = (flat / 27) * 256;
  const int lda = 768, ldb = 768, nkt = 12;

  __shared__ u16 smem[65536];

  const int tid = threadIdx.x;
  const int l = tid & 63;
  const int wid = tid >> 6;
  const int wm = wid >> 1, wn = wid & 1;

  const int r0s = wid * 16 + (l >> 3);
  const int ces = ((l & 7) ^ (l >> 3)) << 3;
  const size_t aR0 = (size_t)(m0 + r0s) * lda + ces;
  const size_t aR1 = aR0 + (size_t)8 * lda;
  const size_t bR0 = (size_t)(n0 + r0s) * ldb + ces;
  const size_t bR1 = bR0 + (size_t)8 * ldb;
  const size_t hA = (size_t)128 * lda, hB = (size_t)128 * ldb;
  const int dst0 = wid * 1024 + l * 8, dst1 = dst0 + 512;
  u16* As0 = smem;
  u16* Bs0 = smem + 32768;

#define STAGE_A(bf, h, kkv) do {                                 \
    u16* Lp = As0 + (bf) * 16384 + (h) * 8192;                   \
    load_lds16(A + aR0 + ((h) ? hA : 0) + (kkv), Lp + dst0);     \
    load_lds16(A + aR1 + ((h) ? hA : 0) + (kkv), Lp + dst1);     \
  } while (0)
#define STAGE_B(bf, h, kkv) do {                                 \
    u16* Lp = Bs0 + (bf) * 16384 + (h) * 8192;                   \
    load_lds16(B + bR0 + ((h) ? hB : 0) + (kkv), Lp + dst0);     \
    load_lds16(B + bR1 + ((h) ? hB : 0) + (kkv), Lp + dst1);     \
  } while (0)

  f32x4 acc[2][2][2][4] = {};
  bf16x8 af[2][2], bA[4][2], bB[4][2];

#define MFMA16(QM, QN, BARR)                                                  \
    __builtin_amdgcn_s_setprio(1);                                            \
    _Pragma("unroll") for (int ks = 0; ks < 2; ks++)                          \
      _Pragma("unroll") for (int fm = 0; fm < 2; fm++)                        \
        _Pragma("unroll") for (int fn = 0; fn < 4; fn++)                      \
          acc[QM][QN][fm][fn] = __builtin_amdgcn_mfma_f32_16x16x32_bf16(      \
              af[fm][ks], BARR[fn][ks], acc[QM][QN][fm][fn], 0, 0, 0);        \
    __builtin_amdgcn_s_setprio(0);

#define RD_A(half)                                                            \
    _Pragma("unroll") for (int fm = 0; fm < 2; fm++)                          \
      _Pragma("unroll") for (int ks = 0; ks < 2; ks++)                        \
        af[fm][ks] = rdfrag(half, wm * 32 + fm * 16 + (l & 15), ks, l);
#define RD_B(dstv, half)                                                      \
    _Pragma("unroll") for (int fn = 0; fn < 4; fn++)                          \
      _Pragma("unroll") for (int ks = 0; ks < 2; ks++)                        \
        dstv[fn][ks] = rdfrag(half, wn * 64 + fn * 16 + (l & 15), ks, l);

  STAGE_A(0, 0, 0); STAGE_B(0, 0, 0); STAGE_B(0, 1, 0); STAGE_A(0, 1, 0);
  STAGE_A(1, 0, 64); STAGE_B(1, 0, 64); STAGE_B(1, 1, 64);
  VMCNT6();
  BAR();

  for (int t = 0; t < nkt; ++t) {
    const int cur = t & 1, nxt = cur ^ 1;
    const int kk1 = (t + 1) << 6, kk2 = (t + 2) << 6;
    const bool s1 = (t + 1 < nkt), s2 = (t + 2 < nkt);
    RD_A(As0 + cur * 16384);
    RD_B(bA, Bs0 + cur * 16384);
    if (s1) STAGE_A(nxt, 1, kk1);
    BAR();
    MFMA16(0, 0, bA);
    BAR();
    RD_B(bB, Bs0 + cur * 16384 + 8192);
    if (s2) STAGE_A(cur, 0, kk2);
    BAR();
    MFMA16(0, 1, bB);
    BAR();
    RD_A(As0 + cur * 16384 + 8192);
    if (s2) STAGE_B(cur, 0, kk2);
    BAR();
    MFMA16(1, 1, bB);
    BAR();
    if (s2) STAGE_B(cur, 1, kk2);
    BAR();
    MFMA16(1, 0, bA);
    if (s2) { VMCNT6(); } else { VMCNT0(); }
    BAR();
  }
#undef RD_A
#undef RD_B
#undef MFMA16
#undef STAGE_A
#undef STAGE_B

  __syncthreads();
  const int sel = n0 >= 4608 ? 2 : (n0 >= 2304 ? 1 : 0);
  const int r0c = (l >> 4) << 2;
  if (sel == 2) {
#pragma unroll
    for (int Qm = 0; Qm < 2; Qm++)
#pragma unroll
      for (int Qn = 0; Qn < 2; Qn++)
#pragma unroll
        for (int fn = 0; fn < 4; fn++) {
          const int coll = Qn * 128 + wn * 64 + fn * 16 + (l & 15);
          const float bv = bias[n0 + coll];
#pragma unroll
          for (int fm = 0; fm < 2; fm++)
#pragma unroll
            for (int r = 0; r < 4; r++) {
              const int rowl = Qm * 128 + wm * 32 + fm * 16 + r0c + r;
              smem[coll * 256 + ((((rowl >> 3) ^ (coll & 7)) << 3) | (rowl & 7))] =
                  bf16bits(acc[Qm][Qn][fm][fn][r] + bv);
            }
        }
    __syncthreads();
    const int n0v = n0 - 4608;
    const int h = n0v / 768, d0l = n0v % 768;
    const int b = m0 >> 11, sbase = m0 & 2047;
    u16* Cb = Vt + ((size_t)(b * 3 + h) * 768 + d0l) * 2048 + sbase;
#pragma unroll
    for (int j = 0; j < 16; j++) {
      const int dr = j * 16 + (tid >> 5);
      const int c8 = tid & 31;
      bf16x8 v = *(const bf16x8*)&smem[dr * 256 + ((c8 ^ (dr & 7)) << 3)];
      *(bf16x8*)&Cb[(size_t)dr * 2048 + c8 * 8] = v;
    }
  } else {
#pragma unroll
    for (int Qm = 0; Qm < 2; Qm++)
#pragma unroll
      for (int Qn = 0; Qn < 2; Qn++)
#pragma unroll
        for (int fn = 0; fn < 4; fn++) {
          const int coll = Qn * 128 + wn * 64 + fn * 16 + (l & 15);
          const float bv = bias[n0 + coll];
#pragma unroll
          for (int fm = 0; fm < 2; fm++)
#pragma unroll
            for (int r = 0; r < 4; r++) {
              const int rowl = Qm * 128 + wm * 32 + fm * 16 + r0c + r;
              smem[rowl * 256 + (coll ^ (((rowl >> 2) & 3) << 4))] =
                  bf16bits(acc[Qm][Qn][fm][fn][r] + bv);
            }
        }
    __syncthreads();
    u16* Cb = C + (size_t)sel * (8192ull * 2304) + (n0 - sel * 2304);
#pragma unroll
    for (int j = 0; j < 16; j++) {
      const int rowl = j * 16 + (tid >> 5);
      const int c = (tid & 31) * 8;
      bf16x8 v = *(const bf16x8*)&smem[rowl * 256 + (c ^ (((rowl >> 2) & 3) << 4))];
      *(bf16x8*)&Cb[(size_t)(m0 + rowl) * 2304 + c] = v;
    }
  }
}

// ---------------- 128x256 engine (8 waves, BK=32, triple-buffer) -------------
// 2 blocks/CU, ONE barrier per K-tile. G128_PV fuses softmax normalization via
// ftab. G128_WO fuses: ab = bf16(a + x) out (yb) + per-block partial sum of a.
template<int MODE>
__global__ __launch_bounds__(512, 4) void k_g128(
    const u16* __restrict__ Abase, const u16* __restrict__ Bbase,
    const float* __restrict__ bias, void* __restrict__ Cbase,
    float* __restrict__ part, const float* __restrict__ xin,
    long lda, long ldb, long ldc, int K, OffN off)
{
  int m0, n0, z, r = 0, rb = 0, nkt, arow0, brow0;
  const u16 *A, *B;
  if (MODE == G128_SC) {
    r = 15 - (int)blockIdx.y;                  // heavy row-blocks first
    z = blockIdx.z;
    rb = r >> 1;
    if ((int)blockIdx.x > rb) return;
    m0 = r * 128; n0 = blockIdx.x * 256;
    nkt = K >> 5;
    A = Abase + off.a[z]; B = Bbase + off.b[z];
    arow0 = m0; brow0 = n0;
  } else if (MODE == G128_PV) {
    r = 15 - (int)blockIdx.y;                  // heavy row-blocks first
    rb = r >> 1;
    z = blockIdx.x / 3;
    m0 = r * 128; n0 = (blockIdx.x % 3) * 256;
    nkt = (rb + 1) * 8;                        // K = (rb+1)*256, BK=32
    lda = (long)(rb + 1) * 256;                // packed bf16 P pitch
    A = Abase + off.a[z] + (size_t)32768 * rb * (rb + 1);
    B = Bbase + off.b[z];
    arow0 = (r & 1) * 128; brow0 = n0;
  } else {
    z = 0;
    m0 = blockIdx.y * 128; n0 = blockIdx.x * 256;
    nkt = K >> 5;
    A = Abase; B = Bbase;
    arow0 = m0; brow0 = n0;
  }

  __shared__ u16 smem[39168];                  // 72KB buffers + 4.6KB ftab/red

  const int tid = threadIdx.x;
  const int l = tid & 63;
  const int wid = tid >> 6;
  const int wm = wid & 1;                      // 2 x 64-row slices
  const int wn = wid >> 1;                     // 4 x 64-col slices

  const int ces = (((tid & 3) ^ ((tid >> 3) & 3)) << 3);
  const u16* aS  = A + (size_t)(arow0 + (tid >> 2)) * lda + ces;
  const u16* bS0 = B + (size_t)(brow0 + (tid >> 2)) * ldb + ces;
  const u16* bS1 = bS0 + (size_t)128 * ldb;
  const int t8 = tid * 8;

#define STG(buf, kkv) do {                         \
    u16* Lp = smem + (buf) * 12288;                \
    load_lds16(aS + (kkv), Lp + t8);               \
    load_lds16(bS0 + (kkv), Lp + 4096 + t8);       \
    load_lds16(bS1 + (kkv), Lp + 8192 + t8);       \
  } while (0)

  float* ftab = (float*)(smem + 36864);        // [128][9] (PV only)
  if (MODE == G128_PV) {
    if (tid < 128) {
      const float2* pp = (const float2*)part + (size_t)z * 16384 + (m0 + tid);
      float m = -1e30f;
      for (int t = 0; t <= rb; t++) m = fmaxf(m, pp[(size_t)t * 2048].x);
      float den = 0.f;
      for (int t = 0; t <= rb; t++) {
        const float2 q = pp[(size_t)t * 2048];
        const float e = __expf(q.x - m);
        den += q.y * e;
        ftab[tid * 9 + t] = e;
      }
      ftab[tid * 9 + 8] = 1.f / den;
    }
    LGKM0();
  }

  f32x4 acc[4][4] = {};
  bf16x8 af[4], bf[4];

  STG(0, 0);
  STG(1, 32);
  VMCNT3();
  BAR();

  for (int t = 0; t < nkt; ++t) {
    const u16* Ar = smem + (t % 3) * 12288;
    const u16* Br = Ar + 4096;
#pragma unroll
    for (int fm = 0; fm < 4; fm++)
      af[fm] = rdfrag32(Ar, wm * 64 + fm * 16 + (l & 15), l);
#pragma unroll
    for (int fn = 0; fn < 4; fn++)
      bf[fn] = rdfrag32(Br, wn * 64 + fn * 16 + (l & 15), l);
    if (MODE == G128_PV) {                     // scale A-frags by exp(m_t - m)
      const int tcol = t >> 3;
#pragma unroll
      for (int fm = 0; fm < 4; fm++) {
        const int row = wm * 64 + fm * 16 + (l & 15);
        const float ft = ftab[row * 9 + tcol];
#pragma unroll
        for (int i = 0; i < 8; i++)
          af[fm][i] = (__bf16)((float)af[fm][i] * ft);
      }
    }
    const bool s2 = (t + 2 < nkt);
    if (s2) STG((t + 2) % 3, (t + 2) << 5);
    __builtin_amdgcn_s_setprio(1);
#pragma unroll
    for (int fm = 0; fm < 4; fm++)
#pragma unroll
      for (int fn = 0; fn < 4; fn++)
        acc[fm][fn] = __builtin_amdgcn_mfma_f32_16x16x32_bf16(
            af[fm], bf[fn], acc[fm][fn], 0, 0, 0);
    __builtin_amdgcn_s_setprio(0);
    if (s2) { VMCNT3(); } else if (t + 1 < nkt) { VMCNT0(); }
    BAR();
  }
#undef STG

  const int r0c = (l >> 4) << 2;
  if (MODE == G128_SC) {
    float mx4[4][4], s4[4][4];
#pragma unroll
    for (int fm = 0; fm < 4; fm++)
#pragma unroll
      for (int rr = 0; rr < 4; rr++) {
        const int gi = m0 + wm * 64 + fm * 16 + r0c + rr;
        float mv = -1e30f;
#pragma unroll
        for (int fn = 0; fn < 4; fn++) {
          const int gc = n0 + wn * 64 + fn * 16 + (l & 15);
          float v = (gc <= gi) ? acc[fm][fn][rr] : -1e30f;
          acc[fm][fn][rr] = v;
          mv = fmaxf(mv, v);
        }
        mx4[fm][rr] = mv;
      }
#pragma unroll
    for (int o = 1; o < 16; o <<= 1)
#pragma unroll
      for (int fm = 0; fm < 4; fm++)
#pragma unroll
        for (int rr = 0; rr < 4; rr++)
          mx4[fm][rr] = fmaxf(mx4[fm][rr], __shfl_xor(mx4[fm][rr], o, 64));
    float* redm = (float*)smem;          // [128][4]
    float* reds = redm + 512;            // [128][4]
#pragma unroll
    for (int fm = 0; fm < 4; fm++)
#pragma unroll
      for (int rr = 0; rr < 4; rr++)
        if ((l & 15) == fm * 4 + rr)
          redm[(wm * 64 + fm * 16 + r0c + rr) * 4 + wn] = mx4[fm][rr];
    __syncthreads();
#pragma unroll
    for (int fm = 0; fm < 4; fm++)
#pragma unroll
      for (int rr = 0; rr < 4; rr++) {
        const int rowl = wm * 64 + fm * 16 + r0c + rr;
        f32x4 rm = *(const f32x4*)&redm[rowl * 4];
        const float tm = fmaxf(fmaxf(rm[0], rm[1]), fmaxf(rm[2], rm[3]));
        float ss = 0.f;
#pragma unroll
        for (int fn = 0; fn < 4; fn++) {
          const float e = __expf(acc[fm][fn][rr] - tm);
          acc[fm][fn][rr] = e;
          ss += e;
        }
        s4[fm][rr] = ss;
      }
#pragma unroll
    for (int o = 1; o < 16; o <<= 1)
#pragma unroll
      for (int fm = 0; fm < 4; fm++)
#pragma unroll
        for (int rr = 0; rr < 4; rr++)
          s4[fm][rr] += __shfl_xor(s4[fm][rr], o, 64);
#pragma unroll
    for (int fm = 0; fm < 4; fm++)
#pragma unroll
      for (int rr = 0; rr < 4; rr++)
        if ((l & 15) == fm * 4 + rr)
          reds[(wm * 64 + fm * 16 + r0c + rr) * 4 + wn] = s4[fm][rr];
    __syncthreads();
    if (tid < 128) {
      f32x4 rm = *(const f32x4*)&redm[tid * 4];
      f32x4 rs = *(const f32x4*)&reds[tid * 4];
      float2 pw;
      pw.x = fmaxf(fmaxf(rm[0], rm[1]), fmaxf(rm[2], rm[3]));
      pw.y = rs[0] + rs[1] + rs[2] + rs[3];
      ((float2*)part)[((size_t)z * 8 + blockIdx.x) * 2048 + m0 + tid] = pw;
    }
    __syncthreads();
#pragma unroll
    for (int fn = 0; fn < 4; fn++) {
      const int coll = wn * 64 + fn * 16 + (l & 15);
#pragma unroll
      for (int fm = 0; fm < 4; fm++)
#pragma unroll
        for (int rr = 0; rr < 4; rr++) {
          const int rowl = wm * 64 + fm * 16 + r0c + rr;
          smem[rowl * 256 + (coll ^ (((rowl >> 2) & 3) << 4))] =
              bf16bits(acc[fm][fn][rr]);
        }
    }
    __syncthreads();
    u16* Cb = (u16*)Cbase + off.c[z] + (size_t)32768 * rb * (rb + 1);
    const int W = (rb + 1) << 8;
    const int pr0 = (r & 1) * 128;
#pragma unroll
    for (int j = 0; j < 8; j++) {
      const int rowl = j * 16 + (tid >> 5);
      const int c = (tid & 31) * 8;
      bf16x8 v = *(const bf16x8*)&smem[rowl * 256 + (c ^ (((rowl >> 2) & 3) << 4))];
      *(bf16x8*)&Cb[(size_t)(pr0 + rowl) * W + n0 + c] = v;
    }
  } else if (MODE == G128_PV) {
    __syncthreads();
#pragma unroll
    for (int fn = 0; fn < 4; fn++) {
      const int coll = wn * 64 + fn * 16 + (l & 15);
#pragma unroll
      for (int fm = 0; fm < 4; fm++)
#pragma unroll
        for (int rr = 0; rr < 4; rr++) {
          const int rowl = wm * 64 + fm * 16 + r0c + rr;
          smem[rowl * 256 + (coll ^ (((rowl >> 2) & 3) << 4))] =
              bf16bits(acc[fm][fn][rr] * ftab[rowl * 9 + 8]);
        }
    }
    __syncthreads();
    u16* Cb = (u16*)Cbase + off.c[z] + n0;
#pragma unroll
    for (int j = 0; j < 8; j++) {
      const int rowl = j * 16 + (tid >> 5);
      const int c = (tid & 31) * 8;
      bf16x8 v = *(const bf16x8*)&smem[rowl * 256 + (c ^ (((rowl >> 2) & 3) << 4))];
      *(bf16x8*)&Cb[(size_t)(m0 + rowl) * 2304 + c] = v;
    }
  } else if (MODE == G128_WO) {
    // a = acc + bo ; stage bf16(a + x) ; accumulate block partial sum of a
    float lsum = 0.f;
    __syncthreads();
#pragma unroll
    for (int fn = 0; fn < 4; fn++) {
      const int coll = wn * 64 + fn * 16 + (l & 15);
      const float bv = bias[n0 + coll];
#pragma unroll
      for (int fm = 0; fm < 4; fm++)
#pragma unroll
        for (int rr = 0; rr < 4; rr++) {
          const int rowl = wm * 64 + fm * 16 + r0c + rr;
          const float a_val = acc[fm][fn][rr] + bv;
          lsum += a_val;
          const float y = a_val + xin[(size_t)(m0 + rowl) * 768 + n0 + coll];
          smem[rowl * 256 + (coll ^ (((rowl >> 2) & 3) << 4))] = bf16bits(y);
        }
    }
#pragma unroll
    for (int o = 32; o >= 1; o >>= 1) lsum += __shfl_xor(lsum, o, 64);
    float* red = (float*)(smem + 32768);
    if (l == 0) red[wid] = lsum;
    __syncthreads();
    if (tid == 0) {
      float s = 0.f;
#pragma unroll
      for (int i = 0; i < 8; i++) s += red[i];
      part[blockIdx.y * 3 + blockIdx.x] = s;
    }
    u16* Cb = (u16*)Cbase + n0;
#pragma unroll
    for (int j = 0; j < 8; j++) {
      const int rowl = j * 16 + (tid >> 5);
      const int c = (tid & 31) * 8;
      bf16x8 v = *(const bf16x8*)&smem[rowl * 256 + (c ^ (((rowl >> 2) & 3) << 4))];
      *(bf16x8*)&Cb[(size_t)(m0 + rowl) * ldc + c] = v;
    }
  } else {
#pragma unroll
    for (int fn = 0; fn < 4; fn++) {
      const int col = n0 + wn * 64 + fn * 16 + (l & 15);
      const float bv = bias[col];
#pragma unroll
      for (int fm = 0; fm < 4; fm++)
#pragma unroll
        for (int rr = 0; rr < 4; rr++) {
          const int rowl = wm * 64 + fm * 16 + r0c + rr;
          float v = acc[fm][fn][rr] + bv;
          v = v > 0.f ? v : 0.01f * v;
          ((float*)Cbase)[(size_t)(m0 + rowl) * ldc + col] = v;
        }
    }
  }
}

// ---------------- helpers ----------------
__global__ __launch_bounds__(256) void k_cast_x(const float* __restrict__ in,
                                                u16* __restrict__ out) {
  const size_t i = ((size_t)blockIdx.x * 256 + threadIdx.x) * 4;
  float4 v = *(const float4*)&in[i];
  ushort4 o;
  o.x = bf16bits(v.x); o.y = bf16bits(v.y); o.z = bf16bits(v.z); o.w = bf16bits(v.w);
  *(ushort4*)&out[i] = o;
}

__global__ __launch_bounds__(256) void k_wt3(const float* __restrict__ w0,
                                             const float* __restrict__ w1,
                                             const float* __restrict__ w2,
                                             u16* __restrict__ out) {
  const float* in = blockIdx.z == 0 ? w0 : (blockIdx.z == 1 ? w1 : w2);
  u16* o = out + (size_t)blockIdx.z * 2304 * 768;
  __shared__ float tile[32][33];
  const int c0 = blockIdx.x * 32, r0 = blockIdx.y * 32;
  const int tx = threadIdx.x, ty = threadIdx.y;
#pragma unroll
  for (int k = 0; k < 4; k++)
    tile[ty + 8 * k][tx] = in[(size_t)(r0 + ty + 8 * k) * 2304 + c0 + tx];
  __syncthreads();
#pragma unroll
  for (int k = 0; k < 4; k++)
    o[(size_t)(c0 + ty + 8 * k) * 768 + r0 + tx] = bf16bits(tile[tx][ty + 8 * k]);
}

__global__ __launch_bounds__(256) void k_wt(const float* __restrict__ in,
                                            u16* __restrict__ out, int R, int C) {
  __shared__ float tile[32][33];
  const int c0 = blockIdx.x * 32, r0 = blockIdx.y * 32;
  const int tx = threadIdx.x, ty = threadIdx.y;
#pragma unroll
  for (int k = 0; k < 4; k++)
    tile[ty + 8 * k][tx] = in[(size_t)(r0 + ty + 8 * k) * C + c0 + tx];
  __syncthreads();
#pragma unroll
  for (int k = 0; k < 4; k++)
    out[(size_t)(c0 + ty + 8 * k) * R + r0 + tx] = bf16bits(tile[tx][ty + 8 * k]);
}

__global__ __launch_bounds__(256) void k_bias_concat(const float* __restrict__ bq,
                                                     const float* __restrict__ bk,
                                                     const float* __restrict__ bv,
                                                     float* __restrict__ out) {
  const int i = blockIdx.x * 256 + threadIdx.x;
  if (i < 2304) out[i] = bq[i];
  else if (i < 4608) out[i] = bk[i - 2304];
  else if (i < 6912) out[i] = bv[i - 4608];
}

// mean over 192 Wo-block partials
__global__ __launch_bounds__(256) void k_mean(const float* __restrict__ part,
                                              float* __restrict__ mean) {
  const int t = threadIdx.x;
  float s = (t < 192) ? part[t] : 0.f;
#pragma unroll
  for (int o = 32; o >= 1; o >>= 1) s += __shfl_xor(s, o, 64);
  __shared__ float r[4];
  const int w = t >> 6;
  if ((t & 63) == 0) r[w] = s;
  __syncthreads();
  if (t == 0) mean[0] = (r[0] + r[1] + r[2] + r[3]) * (1.f / 6291456.f);
}

// bf'[j] = bf[j] - mean * colsum(Wf)[j]
__global__ __launch_bounds__(256) void k_ffbias(const float* __restrict__ Wf,
                                                const float* __restrict__ bfb,
                                                const float* __restrict__ meanp,
                                                float* __restrict__ out) {
  const int j = blockIdx.x * 256 + threadIdx.x;
  float s = 0.f;
  for (int k = 0; k < 768; k++) s += Wf[(size_t)k * 768 + j];
  out[j] = bfb[j] - meanp[0] * s;
}

extern "C" void kernel_launch(void* const* d_in, const int* in_sizes, int n_in,
                              void* d_out, int out_size, void* d_ws, size_t ws_size,
                              hipStream_t stream) {
  const float* x   = (const float*)d_in[0];
  const float* Wq  = (const float*)d_in[1];
  const float* bq  = (const float*)d_in[2];
  const float* Wk  = (const float*)d_in[3];
  const float* bk  = (const float*)d_in[4];
  const float* Wv  = (const float*)d_in[5];
  const float* bv  = (const float*)d_in[6];
  const float* Wo  = (const float*)d_in[7];
  const float* bo  = (const float*)d_in[8];
  const float* Wf  = (const float*)d_in[9];
  const float* bfb = (const float*)d_in[10];

  char* ws = (char*)d_ws;
  const size_t MSZ    = 37748736;                 // 8192*2304*2
  const size_t o_Wqkvt = 0;                       // 10,616,832
  const size_t o_Wot  = 10616832;                 // 3,538,944
  const size_t o_Wft  = o_Wot + 3538944;          // 1,179,648
  const size_t o_bqkv = o_Wft + 1179648;          // 32,768
  const size_t o_prt  = o_bqkv + 32768;           // 8,192 (Wo partials, 192)
  const size_t o_mn   = o_prt + 8192;             // 256
  const size_t o_bff  = o_mn + 256;               // 4,096 (adjusted FF bias)
  const size_t o_part = o_bff + 4096;             // 12*8*2048*8 = 1,572,864
  const size_t o_xb   = o_part + 1572864;         // 12,582,912
  const size_t o_Q    = o_xb + 12582912;
  const size_t o_K    = o_Q + MSZ;
  const size_t o_Vt   = o_K + MSZ;
  const size_t o_P    = o_Vt + MSZ;               // 56,623,104
  const size_t o_end  = o_P + 56623104;           // ~199.4 MB
  if (ws_size < o_end) return;

  const size_t o_O  = o_Q;   // Q dead after scores
  const size_t o_yb = o_xb;  // xb dead after QKV

  OffN z0{};
  dim3 b32(32, 8);

  k_cast_x<<<6144, 256, 0, stream>>>(x, (u16*)(ws + o_xb));
  k_wt3<<<dim3(72, 24, 3), b32, 0, stream>>>(Wq, Wk, Wv, (u16*)(ws + o_Wqkvt));
  k_wt<<<dim3(24, 72), b32, 0, stream>>>(Wo, (u16*)(ws + o_Wot), 2304, 768);
  k_wt<<<dim3(24, 24), b32, 0, stream>>>(Wf, (u16*)(ws + o_Wft), 768, 768);
  k_bias_concat<<<27, 256, 0, stream>>>(bq, bk, bv, (float*)(ws + o_bqkv));

  k_qkv256<<<dim3(27, 32), 512, 0, stream>>>(
      (const u16*)(ws + o_xb), (const u16*)(ws + o_Wqkvt),
      (const float*)(ws + o_bqkv), (u16*)(ws + o_Q), (u16*)(ws + o_Vt));

  // single-chunk attention: all 12 heads; rescale fused into PV
  OffN so{}, po{};
  for (int zz = 0; zz < 12; zz++) {
    const int b = zz / 3, h = zz % 3;
    so.a[zz] = (size_t)b * 2048 * 2304 + (size_t)h * 768;   // Q (u16)
    so.b[zz] = so.a[zz];                                     // K (u16)
    so.c[zz] = (size_t)zz * 2359296;                         // P (u16)
    po.a[zz] = so.c[zz];                                     // P (u16)
    po.b[zz] = (size_t)zz * 768 * 2048;                      // Vt (u16)
    po.c[zz] = so.a[zz];                                     // O (u16)
  }
  k_g128<G128_SC><<<dim3(8, 16, 12), 512, 0, stream>>>(
      (const u16*)(ws + o_Q), (const u16*)(ws + o_K), nullptr, ws + o_P,
      (float*)(ws + o_part), nullptr, 2304, 2304, 0, 768, so);
  k_g128<G128_PV><<<dim3(36, 16), 512, 0, stream>>>(
      (const u16*)(ws + o_P), (const u16*)(ws + o_Vt), nullptr, ws + o_O,
      (float*)(ws + o_part), nullptr, 0, 2048, 0, 0, po);

  // Wo fused: yb = bf16(a + x), partial sums of a -> o_prt
  k_g128<G128_WO><<<dim3(3, 64), 512, 0, stream>>>(
      (const u16*)(ws + o_O), (const u16*)(ws + o_Wot), bo, ws + o_yb,
      (float*)(ws + o_prt), x, 2304, 2304, 768, 2304, z0);

  k_mean<<<1, 256, 0, stream>>>((const float*)(ws + o_prt), (float*)(ws + o_mn));
  k_ffbias<<<3, 256, 0, stream>>>(Wf, bfb, (const float*)(ws + o_mn),
                                  (float*)(ws + o_bff));

  k_g128<G128_LEAKY><<<dim3(3, 64), 512, 0, stream>>>(
      (const u16*)(ws + o_yb), (const u16*)(ws + o_Wft),
      (const float*)(ws + o_bff), d_out,
      nullptr, nullptr, 768, 768, 768, 768, z0);
}

// Round 15
// 369.860 us; speedup vs baseline: 1.0497x; 1.0497x over previous
//
#include <hip/hip_runtime.h>
#include <hip/hip_bf16.h>

typedef __attribute__((ext_vector_type(8))) __bf16 bf16x8;
typedef __attribute__((ext_vector_type(4))) float f32x4;
typedef unsigned short u16;

#define DEV static __device__ __forceinline__

#define BAR() asm volatile("s_barrier" ::: "memory")
#define LGKM0() asm volatile("s_waitcnt lgkmcnt(0)" ::: "memory")
#define VMCNT6() asm volatile("s_waitcnt vmcnt(6)" ::: "memory")
#define VMCNT3() asm volatile("s_waitcnt vmcnt(3)" ::: "memory")
#define VMCNT0() asm volatile("s_waitcnt vmcnt(0)" ::: "memory")

DEV void load_lds16(const void* g, void* l) {
  __builtin_amdgcn_global_load_lds(
      (const __attribute__((address_space(1))) unsigned int*)g,
      (__attribute__((address_space(3))) unsigned int*)l, 16, 0, 0);
}

DEV u16 bf16bits(float v) {
  __hip_bfloat16 h = __float2bfloat16(v);
  return __builtin_bit_cast(u16, h);
}

// BK=64 swizzled frag read (rows 128B; conflict-free, key l&7)
DEV bf16x8 rdfrag(const u16* region, int row, int ks, int l) {
  const int cb = (((ks << 6) | ((l >> 4) << 4)) ^ ((l & 7) << 4));
  return *(const bf16x8*)((const char*)region + row * 128 + cb);
}

// BK=32 swizzled frag read (rows 64B; key (row>>1)&3, verified 0-conflict)
DEV bf16x8 rdfrag32(const u16* region, int row, int l) {
  const int cb = (((l >> 4) ^ ((row >> 1) & 3)) << 4);
  return *(const bf16x8*)((const char*)region + row * 64 + cb);
}

struct OffN { unsigned long long a[12], b[12], c[12]; };

enum { G128_SC = 0, G128_PV = 1, G128_WO = 2, G128_LEAKY = 3 };

// ---------------- QKV 256x256 deep-pipelined GEMM (8 waves, BK=64) -----------
__global__ __launch_bounds__(512, 1) void k_qkv256(
    const u16* __restrict__ A, const u16* __restrict__ B,
    const float* __restrict__ bias, u16* __restrict__ C, u16* __restrict__ Vt)
{
  int flat = blockIdx.y * 27 + blockIdx.x;       // 864 = 8 * 108, bijective
  flat = (flat & 7) * 108 + (flat >> 3);
  const int n0 = (flat % 27) * 256, m0 = (flat / 27) * 256;
  const int lda = 768, ldb = 768, nkt = 12;

  __shared__ u16 smem[65536];

  const int tid = threadIdx.x;
  const int l = tid & 63;
  const int wid = tid >> 6;
  const int wm = wid >> 1, wn = wid & 1;

  const int r0s = wid * 16 + (l >> 3);
  const int ces = ((l & 7) ^ (l >> 3)) << 3;
  const size_t aR0 = (size_t)(m0 + r0s) * lda + ces;
  const size_t aR1 = aR0 + (size_t)8 * lda;
  const size_t bR0 = (size_t)(n0 + r0s) * ldb + ces;
  const size_t bR1 = bR0 + (size_t)8 * ldb;
  const size_t hA = (size_t)128 * lda, hB = (size_t)128 * ldb;
  const int dst0 = wid * 1024 + l * 8, dst1 = dst0 + 512;
  u16* As0 = smem;
  u16* Bs0 = smem + 32768;

#define STAGE_A(bf, h, kkv) do {                                 \
    u16* Lp = As0 + (bf) * 16384 + (h) * 8192;                   \
    load_lds16(A + aR0 + ((h) ? hA : 0) + (kkv), Lp + dst0);     \
    load_lds16(A + aR1 + ((h) ? hA : 0) + (kkv), Lp + dst1);     \
  } while (0)
#define STAGE_B(bf, h, kkv) do {                                 \
    u16* Lp = Bs0 + (bf) * 16384 + (h) * 8192;                   \
    load_lds16(B + bR0 + ((h) ? hB : 0) + (kkv), Lp + dst0);     \
    load_lds16(B + bR1 + ((h) ? hB : 0) + (kkv), Lp + dst1);     \
  } while (0)

  f32x4 acc[2][2][2][4] = {};
  bf16x8 af[2][2], bA[4][2], bB[4][2];

#define MFMA16(QM, QN, BARR)                                                  \
    __builtin_amdgcn_s_setprio(1);                                            \
    _Pragma("unroll") for (int ks = 0; ks < 2; ks++)                          \
      _Pragma("unroll") for (int fm = 0; fm < 2; fm++)                        \
        _Pragma("unroll") for (int fn = 0; fn < 4; fn++)                      \
          acc[QM][QN][fm][fn] = __builtin_amdgcn_mfma_f32_16x16x32_bf16(      \
              af[fm][ks], BARR[fn][ks], acc[QM][QN][fm][fn], 0, 0, 0);        \
    __builtin_amdgcn_s_setprio(0);

#define RD_A(half)                                                            \
    _Pragma("unroll") for (int fm = 0; fm < 2; fm++)                          \
      _Pragma("unroll") for (int ks = 0; ks < 2; ks++)                        \
        af[fm][ks] = rdfrag(half, wm * 32 + fm * 16 + (l & 15), ks, l);
#define RD_B(dstv, half)                                                      \
    _Pragma("unroll") for (int fn = 0; fn < 4; fn++)                          \
      _Pragma("unroll") for (int ks = 0; ks < 2; ks++)                        \
        dstv[fn][ks] = rdfrag(half, wn * 64 + fn * 16 + (l & 15), ks, l);

  STAGE_A(0, 0, 0); STAGE_B(0, 0, 0); STAGE_B(0, 1, 0); STAGE_A(0, 1, 0);
  STAGE_A(1, 0, 64); STAGE_B(1, 0, 64); STAGE_B(1, 1, 64);
  VMCNT6();
  BAR();

  for (int t = 0; t < nkt; ++t) {
    const int cur = t & 1, nxt = cur ^ 1;
    const int kk1 = (t + 1) << 6, kk2 = (t + 2) << 6;
    const bool s1 = (t + 1 < nkt), s2 = (t + 2 < nkt);
    RD_A(As0 + cur * 16384);
    RD_B(bA, Bs0 + cur * 16384);
    if (s1) STAGE_A(nxt, 1, kk1);
    BAR();
    MFMA16(0, 0, bA);
    BAR();
    RD_B(bB, Bs0 + cur * 16384 + 8192);
    if (s2) STAGE_A(cur, 0, kk2);
    BAR();
    MFMA16(0, 1, bB);
    BAR();
    RD_A(As0 + cur * 16384 + 8192);
    if (s2) STAGE_B(cur, 0, kk2);
    BAR();
    MFMA16(1, 1, bB);
    BAR();
    if (s2) STAGE_B(cur, 1, kk2);
    BAR();
    MFMA16(1, 0, bA);
    if (s2) { VMCNT6(); } else { VMCNT0(); }
    BAR();
  }
#undef RD_A
#undef RD_B
#undef MFMA16
#undef STAGE_A
#undef STAGE_B

  __syncthreads();
  const int sel = n0 >= 4608 ? 2 : (n0 >= 2304 ? 1 : 0);
  const int r0c = (l >> 4) << 2;
  if (sel == 2) {
#pragma unroll
    for (int Qm = 0; Qm < 2; Qm++)
#pragma unroll
      for (int Qn = 0; Qn < 2; Qn++)
#pragma unroll
        for (int fn = 0; fn < 4; fn++) {
          const int coll = Qn * 128 + wn * 64 + fn * 16 + (l & 15);
          const float bv = bias[n0 + coll];
#pragma unroll
          for (int fm = 0; fm < 2; fm++)
#pragma unroll
            for (int r = 0; r < 4; r++) {
              const int rowl = Qm * 128 + wm * 32 + fm * 16 + r0c + r;
              smem[coll * 256 + ((((rowl >> 3) ^ (coll & 7)) << 3) | (rowl & 7))] =
                  bf16bits(acc[Qm][Qn][fm][fn][r] + bv);
            }
        }
    __syncthreads();
    const int n0v = n0 - 4608;
    const int h = n0v / 768, d0l = n0v % 768;
    const int b = m0 >> 11, sbase = m0 & 2047;
    u16* Cb = Vt + ((size_t)(b * 3 + h) * 768 + d0l) * 2048 + sbase;
#pragma unroll
    for (int j = 0; j < 16; j++) {
      const int dr = j * 16 + (tid >> 5);
      const int c8 = tid & 31;
      bf16x8 v = *(const bf16x8*)&smem[dr * 256 + ((c8 ^ (dr & 7)) << 3)];
      *(bf16x8*)&Cb[(size_t)dr * 2048 + c8 * 8] = v;
    }
  } else {
#pragma unroll
    for (int Qm = 0; Qm < 2; Qm++)
#pragma unroll
      for (int Qn = 0; Qn < 2; Qn++)
#pragma unroll
        for (int fn = 0; fn < 4; fn++) {
          const int coll = Qn * 128 + wn * 64 + fn * 16 + (l & 15);
          const float bv = bias[n0 + coll];
#pragma unroll
          for (int fm = 0; fm < 2; fm++)
#pragma unroll
            for (int r = 0; r < 4; r++) {
              const int rowl = Qm * 128 + wm * 32 + fm * 16 + r0c + r;
              smem[rowl * 256 + (coll ^ (((rowl >> 2) & 3) << 4))] =
                  bf16bits(acc[Qm][Qn][fm][fn][r] + bv);
            }
        }
    __syncthreads();
    u16* Cb = C + (size_t)sel * (8192ull * 2304) + (n0 - sel * 2304);
#pragma unroll
    for (int j = 0; j < 16; j++) {
      const int rowl = j * 16 + (tid >> 5);
      const int c = (tid & 31) * 8;
      bf16x8 v = *(const bf16x8*)&smem[rowl * 256 + (c ^ (((rowl >> 2) & 3) << 4))];
      *(bf16x8*)&Cb[(size_t)(m0 + rowl) * 2304 + c] = v;
    }
  }
}

// ---------------- 128x256 engine (8 waves, BK=32, triple-buffer) -------------
// 2 blocks/CU, ONE barrier per K-tile. G128_PV fuses softmax normalization via
// ftab. G128_WO: partial sums of a in acc-order; x added COALESCED in the
// write phase (two float4 per thread); yb = bf16(bf16(a) + x).
template<int MODE>
__global__ __launch_bounds__(512, 4) void k_g128(
    const u16* __restrict__ Abase, const u16* __restrict__ Bbase,
    const float* __restrict__ bias, void* __restrict__ Cbase,
    float* __restrict__ part, const float* __restrict__ xin,
    long lda, long ldb, long ldc, int K, OffN off)
{
  int m0, n0, z, r = 0, rb = 0, nkt, arow0, brow0;
  const u16 *A, *B;
  if (MODE == G128_SC) {
    r = 15 - (int)blockIdx.y;                  // heavy row-blocks first
    z = blockIdx.z;
    rb = r >> 1;
    if ((int)blockIdx.x > rb) return;
    m0 = r * 128; n0 = blockIdx.x * 256;
    nkt = K >> 5;
    A = Abase + off.a[z]; B = Bbase + off.b[z];
    arow0 = m0; brow0 = n0;
  } else if (MODE == G128_PV) {
    r = 15 - (int)blockIdx.y;                  // heavy row-blocks first
    rb = r >> 1;
    z = blockIdx.x / 3;
    m0 = r * 128; n0 = (blockIdx.x % 3) * 256;
    nkt = (rb + 1) * 8;                        // K = (rb+1)*256, BK=32
    lda = (long)(rb + 1) * 256;                // packed bf16 P pitch
    A = Abase + off.a[z] + (size_t)32768 * rb * (rb + 1);
    B = Bbase + off.b[z];
    arow0 = (r & 1) * 128; brow0 = n0;
  } else {
    z = 0;
    m0 = blockIdx.y * 128; n0 = blockIdx.x * 256;
    nkt = K >> 5;
    A = Abase; B = Bbase;
    arow0 = m0; brow0 = n0;
  }

  __shared__ u16 smem[39168];                  // 72KB buffers + 4.6KB ftab/red

  const int tid = threadIdx.x;
  const int l = tid & 63;
  const int wid = tid >> 6;
  const int wm = wid & 1;                      // 2 x 64-row slices
  const int wn = wid >> 1;                     // 4 x 64-col slices

  const int ces = (((tid & 3) ^ ((tid >> 3) & 3)) << 3);
  const u16* aS  = A + (size_t)(arow0 + (tid >> 2)) * lda + ces;
  const u16* bS0 = B + (size_t)(brow0 + (tid >> 2)) * ldb + ces;
  const u16* bS1 = bS0 + (size_t)128 * ldb;
  const int t8 = tid * 8;

#define STG(buf, kkv) do {                         \
    u16* Lp = smem + (buf) * 12288;                \
    load_lds16(aS + (kkv), Lp + t8);               \
    load_lds16(bS0 + (kkv), Lp + 4096 + t8);       \
    load_lds16(bS1 + (kkv), Lp + 8192 + t8);       \
  } while (0)

  float* ftab = (float*)(smem + 36864);        // [128][9] (PV only)
  if (MODE == G128_PV) {
    if (tid < 128) {
      const float2* pp = (const float2*)part + (size_t)z * 16384 + (m0 + tid);
      float m = -1e30f;
      for (int t = 0; t <= rb; t++) m = fmaxf(m, pp[(size_t)t * 2048].x);
      float den = 0.f;
      for (int t = 0; t <= rb; t++) {
        const float2 q = pp[(size_t)t * 2048];
        const float e = __expf(q.x - m);
        den += q.y * e;
        ftab[tid * 9 + t] = e;
      }
      ftab[tid * 9 + 8] = 1.f / den;
    }
    LGKM0();
  }

  f32x4 acc[4][4] = {};
  bf16x8 af[4], bf[4];

  STG(0, 0);
  STG(1, 32);
  VMCNT3();
  BAR();

  for (int t = 0; t < nkt; ++t) {
    const u16* Ar = smem + (t % 3) * 12288;
    const u16* Br = Ar + 4096;
#pragma unroll
    for (int fm = 0; fm < 4; fm++)
      af[fm] = rdfrag32(Ar, wm * 64 + fm * 16 + (l & 15), l);
#pragma unroll
    for (int fn = 0; fn < 4; fn++)
      bf[fn] = rdfrag32(Br, wn * 64 + fn * 16 + (l & 15), l);
    if (MODE == G128_PV) {                     // scale A-frags by exp(m_t - m)
      const int tcol = t >> 3;
#pragma unroll
      for (int fm = 0; fm < 4; fm++) {
        const int row = wm * 64 + fm * 16 + (l & 15);
        const float ft = ftab[row * 9 + tcol];
#pragma unroll
        for (int i = 0; i < 8; i++)
          af[fm][i] = (__bf16)((float)af[fm][i] * ft);
      }
    }
    const bool s2 = (t + 2 < nkt);
    if (s2) STG((t + 2) % 3, (t + 2) << 5);
    __builtin_amdgcn_s_setprio(1);
#pragma unroll
    for (int fm = 0; fm < 4; fm++)
#pragma unroll
      for (int fn = 0; fn < 4; fn++)
        acc[fm][fn] = __builtin_amdgcn_mfma_f32_16x16x32_bf16(
            af[fm], bf[fn], acc[fm][fn], 0, 0, 0);
    __builtin_amdgcn_s_setprio(0);
    if (s2) { VMCNT3(); } else if (t + 1 < nkt) { VMCNT0(); }
    BAR();
  }
#undef STG

  const int r0c = (l >> 4) << 2;
  if (MODE == G128_SC) {
    float mx4[4][4], s4[4][4];
#pragma unroll
    for (int fm = 0; fm < 4; fm++)
#pragma unroll
      for (int rr = 0; rr < 4; rr++) {
        const int gi = m0 + wm * 64 + fm * 16 + r0c + rr;
        float mv = -1e30f;
#pragma unroll
        for (int fn = 0; fn < 4; fn++) {
          const int gc = n0 + wn * 64 + fn * 16 + (l & 15);
          float v = (gc <= gi) ? acc[fm][fn][rr] : -1e30f;
          acc[fm][fn][rr] = v;
          mv = fmaxf(mv, v);
        }
        mx4[fm][rr] = mv;
      }
#pragma unroll
    for (int o = 1; o < 16; o <<= 1)
#pragma unroll
      for (int fm = 0; fm < 4; fm++)
#pragma unroll
        for (int rr = 0; rr < 4; rr++)
          mx4[fm][rr] = fmaxf(mx4[fm][rr], __shfl_xor(mx4[fm][rr], o, 64));
    float* redm = (float*)smem;          // [128][4]
    float* reds = redm + 512;            // [128][4]
#pragma unroll
    for (int fm = 0; fm < 4; fm++)
#pragma unroll
      for (int rr = 0; rr < 4; rr++)
        if ((l & 15) == fm * 4 + rr)
          redm[(wm * 64 + fm * 16 + r0c + rr) * 4 + wn] = mx4[fm][rr];
    __syncthreads();
#pragma unroll
    for (int fm = 0; fm < 4; fm++)
#pragma unroll
      for (int rr = 0; rr < 4; rr++) {
        const int rowl = wm * 64 + fm * 16 + r0c + rr;
        f32x4 rm = *(const f32x4*)&redm[rowl * 4];
        const float tm = fmaxf(fmaxf(rm[0], rm[1]), fmaxf(rm[2], rm[3]));
        float ss = 0.f;
#pragma unroll
        for (int fn = 0; fn < 4; fn++) {
          const float e = __expf(acc[fm][fn][rr] - tm);
          acc[fm][fn][rr] = e;
          ss += e;
        }
        s4[fm][rr] = ss;
      }
#pragma unroll
    for (int o = 1; o < 16; o <<= 1)
#pragma unroll
      for (int fm = 0; fm < 4; fm++)
#pragma unroll
        for (int rr = 0; rr < 4; rr++)
          s4[fm][rr] += __shfl_xor(s4[fm][rr], o, 64);
#pragma unroll
    for (int fm = 0; fm < 4; fm++)
#pragma unroll
      for (int rr = 0; rr < 4; rr++)
        if ((l & 15) == fm * 4 + rr)
          reds[(wm * 64 + fm * 16 + r0c + rr) * 4 + wn] = s4[fm][rr];
    __syncthreads();
    if (tid < 128) {
      f32x4 rm = *(const f32x4*)&redm[tid * 4];
      f32x4 rs = *(const f32x4*)&reds[tid * 4];
      float2 pw;
      pw.x = fmaxf(fmaxf(rm[0], rm[1]), fmaxf(rm[2], rm[3]));
      pw.y = rs[0] + rs[1] + rs[2] + rs[3];
      ((float2*)part)[((size_t)z * 8 + blockIdx.x) * 2048 + m0 + tid] = pw;
    }
    __syncthreads();
#pragma unroll
    for (int fn = 0; fn < 4; fn++) {
      const int coll = wn * 64 + fn * 16 + (l & 15);
#pragma unroll
      for (int fm = 0; fm < 4; fm++)
#pragma unroll
        for (int rr = 0; rr < 4; rr++) {
          const int rowl = wm * 64 + fm * 16 + r0c + rr;
          smem[rowl * 256 + (coll ^ (((rowl >> 2) & 3) << 4))] =
              bf16bits(acc[fm][fn][rr]);
        }
    }
    __syncthreads();
    u16* Cb = (u16*)Cbase + off.c[z] + (size_t)32768 * rb * (rb + 1);
    const int W = (rb + 1) << 8;
    const int pr0 = (r & 1) * 128;
#pragma unroll
    for (int j = 0; j < 8; j++) {
      const int rowl = j * 16 + (tid >> 5);
      const int c = (tid & 31) * 8;
      bf16x8 v = *(const bf16x8*)&smem[rowl * 256 + (c ^ (((rowl >> 2) & 3) << 4))];
      *(bf16x8*)&Cb[(size_t)(pr0 + rowl) * W + n0 + c] = v;
    }
  } else if (MODE == G128_PV) {
    __syncthreads();
#pragma unroll
    for (int fn = 0; fn < 4; fn++) {
      const int coll = wn * 64 + fn * 16 + (l & 15);
#pragma unroll
      for (int fm = 0; fm < 4; fm++)
#pragma unroll
        for (int rr = 0; rr < 4; rr++) {
          const int rowl = wm * 64 + fm * 16 + r0c + rr;
          smem[rowl * 256 + (coll ^ (((rowl >> 2) & 3) << 4))] =
              bf16bits(acc[fm][fn][rr] * ftab[rowl * 9 + 8]);
        }
    }
    __syncthreads();
    u16* Cb = (u16*)Cbase + off.c[z] + n0;
#pragma unroll
    for (int j = 0; j < 8; j++) {
      const int rowl = j * 16 + (tid >> 5);
      const int c = (tid & 31) * 8;
      bf16x8 v = *(const bf16x8*)&smem[rowl * 256 + (c ^ (((rowl >> 2) & 3) << 4))];
      *(bf16x8*)&Cb[(size_t)(m0 + rowl) * 2304 + c] = v;
    }
  } else if (MODE == G128_WO) {
    // a = acc + bo ; stage bf16(a) ; block partial sum of a ; x added in
    // the coalesced write phase.
    float lsum = 0.f;
    __syncthreads();
#pragma unroll
    for (int fn = 0; fn < 4; fn++) {
      const int coll = wn * 64 + fn * 16 + (l & 15);
      const float bv = bias[n0 + coll];
#pragma unroll
      for (int fm = 0; fm < 4; fm++)
#pragma unroll
        for (int rr = 0; rr < 4; rr++) {
          const int rowl = wm * 64 + fm * 16 + r0c + rr;
          const float a_val = acc[fm][fn][rr] + bv;
          lsum += a_val;
          smem[rowl * 256 + (coll ^ (((rowl >> 2) & 3) << 4))] = bf16bits(a_val);
        }
    }
#pragma unroll
    for (int o = 32; o >= 1; o >>= 1) lsum += __shfl_xor(lsum, o, 64);
    float* red = (float*)(smem + 32768);
    if (l == 0) red[wid] = lsum;
    __syncthreads();
    if (tid == 0) {
      float s = 0.f;
#pragma unroll
      for (int i = 0; i < 8; i++) s += red[i];
      part[blockIdx.y * 3 + blockIdx.x] = s;
    }
    u16* Cb = (u16*)Cbase + n0;
    const float* xb = xin + n0;
#pragma unroll
    for (int j = 0; j < 8; j++) {
      const int rowl = j * 16 + (tid >> 5);
      const int c = (tid & 31) * 8;
      bf16x8 v = *(const bf16x8*)&smem[rowl * 256 + (c ^ (((rowl >> 2) & 3) << 4))];
      f32x4 x0 = *(const f32x4*)&xb[(size_t)(m0 + rowl) * 768 + c];
      f32x4 x1 = *(const f32x4*)&xb[(size_t)(m0 + rowl) * 768 + c + 4];
      u16 o8[8];
#pragma unroll
      for (int i = 0; i < 4; i++) o8[i] = bf16bits((float)v[i] + x0[i]);
#pragma unroll
      for (int i = 0; i < 4; i++) o8[4 + i] = bf16bits((float)v[4 + i] + x1[i]);
      *(bf16x8*)&Cb[(size_t)(m0 + rowl) * ldc + c] = *(const bf16x8*)o8;
    }
  } else {
#pragma unroll
    for (int fn = 0; fn < 4; fn++) {
      const int col = n0 + wn * 64 + fn * 16 + (l & 15);
      const float bv = bias[col];
#pragma unroll
      for (int fm = 0; fm < 4; fm++)
#pragma unroll
        for (int rr = 0; rr < 4; rr++) {
          const int rowl = wm * 64 + fm * 16 + r0c + rr;
          float v = acc[fm][fn][rr] + bv;
          v = v > 0.f ? v : 0.01f * v;
          ((float*)Cbase)[(size_t)(m0 + rowl) * ldc + col] = v;
        }
    }
  }
}

// ---------------- helpers ----------------
__global__ __launch_bounds__(256) void k_cast_x(const float* __restrict__ in,
                                                u16* __restrict__ out) {
  const size_t i = ((size_t)blockIdx.x * 256 + threadIdx.x) * 4;
  float4 v = *(const float4*)&in[i];
  ushort4 o;
  o.x = bf16bits(v.x); o.y = bf16bits(v.y); o.z = bf16bits(v.z); o.w = bf16bits(v.w);
  *(ushort4*)&out[i] = o;
}

__global__ __launch_bounds__(256) void k_wt3(const float* __restrict__ w0,
                                             const float* __restrict__ w1,
                                             const float* __restrict__ w2,
                                             u16* __restrict__ out) {
  const float* in = blockIdx.z == 0 ? w0 : (blockIdx.z == 1 ? w1 : w2);
  u16* o = out + (size_t)blockIdx.z * 2304 * 768;
  __shared__ float tile[32][33];
  const int c0 = blockIdx.x * 32, r0 = blockIdx.y * 32;
  const int tx = threadIdx.x, ty = threadIdx.y;
#pragma unroll
  for (int k = 0; k < 4; k++)
    tile[ty + 8 * k][tx] = in[(size_t)(r0 + ty + 8 * k) * 2304 + c0 + tx];
  __syncthreads();
#pragma unroll
  for (int k = 0; k < 4; k++)
    o[(size_t)(c0 + ty + 8 * k) * 768 + r0 + tx] = bf16bits(tile[tx][ty + 8 * k]);
}

__global__ __launch_bounds__(256) void k_wt(const float* __restrict__ in,
                                            u16* __restrict__ out, int R, int C) {
  __shared__ float tile[32][33];
  const int c0 = blockIdx.x * 32, r0 = blockIdx.y * 32;
  const int tx = threadIdx.x, ty = threadIdx.y;
#pragma unroll
  for (int k = 0; k < 4; k++)
    tile[ty + 8 * k][tx] = in[(size_t)(r0 + ty + 8 * k) * C + c0 + tx];
  __syncthreads();
#pragma unroll
  for (int k = 0; k < 4; k++)
    out[(size_t)(c0 + ty + 8 * k) * R + r0 + tx] = bf16bits(tile[tx][ty + 8 * k]);
}

__global__ __launch_bounds__(256) void k_bias_concat(const float* __restrict__ bq,
                                                     const float* __restrict__ bk,
                                                     const float* __restrict__ bv,
                                                     float* __restrict__ out) {
  const int i = blockIdx.x * 256 + threadIdx.x;
  if (i < 2304) out[i] = bq[i];
  else if (i < 4608) out[i] = bk[i - 2304];
  else if (i < 6912) out[i] = bv[i - 4608];
}

// colsum(Wf)[j]: 12 blocks x 64 cols, fixed deterministic partition
__global__ __launch_bounds__(256) void k_colsum(const float* __restrict__ Wf,
                                                float* __restrict__ cs) {
  __shared__ float red[4][64];
  const int col = blockIdx.x * 64 + (threadIdx.x & 63);
  const int rg = threadIdx.x >> 6;
  float s = 0.f;
  for (int i = 0; i < 192; i++)
    s += Wf[(size_t)(rg + 4 * i) * 768 + col];
  red[rg][threadIdx.x & 63] = s;
  __syncthreads();
  if (threadIdx.x < 64)
    cs[blockIdx.x * 64 + threadIdx.x] =
        red[0][threadIdx.x] + red[1][threadIdx.x] +
        red[2][threadIdx.x] + red[3][threadIdx.x];
}

// mean over 192 Wo-block partials
__global__ __launch_bounds__(256) void k_mean(const float* __restrict__ part,
                                              float* __restrict__ mean) {
  const int t = threadIdx.x;
  float s = (t < 192) ? part[t] : 0.f;
#pragma unroll
  for (int o = 32; o >= 1; o >>= 1) s += __shfl_xor(s, o, 64);
  __shared__ float r[4];
  const int w = t >> 6;
  if ((t & 63) == 0) r[w] = s;
  __syncthreads();
  if (t == 0) mean[0] = (r[0] + r[1] + r[2] + r[3]) * (1.f / 6291456.f);
}

// bf'[j] = bf[j] - mean * colsum[j]  (elementwise; colsum precomputed)
__global__ __launch_bounds__(256) void k_ffbias(const float* __restrict__ cs,
                                                const float* __restrict__ bfb,
                                                const float* __restrict__ meanp,
                                                float* __restrict__ out) {
  const int j = blockIdx.x * 256 + threadIdx.x;
  out[j] = bfb[j] - meanp[0] * cs[j];
}

extern "C" void kernel_launch(void* const* d_in, const int* in_sizes, int n_in,
                              void* d_out, int out_size, void* d_ws, size_t ws_size,
                              hipStream_t stream) {
  const float* x   = (const float*)d_in[0];
  const float* Wq  = (const float*)d_in[1];
  const float* bq  = (const float*)d_in[2];
  const float* Wk  = (const float*)d_in[3];
  const float* bk  = (const float*)d_in[4];
  const float* Wv  = (const float*)d_in[5];
  const float* bv  = (const float*)d_in[6];
  const float* Wo  = (const float*)d_in[7];
  const float* bo  = (const float*)d_in[8];
  const float* Wf  = (const float*)d_in[9];
  const float* bfb = (const float*)d_in[10];

  char* ws = (char*)d_ws;
  const size_t MSZ    = 37748736;                 // 8192*2304*2
  const size_t o_Wqkvt = 0;                       // 10,616,832
  const size_t o_Wot  = 10616832;                 // 3,538,944
  const size_t o_Wft  = o_Wot + 3538944;          // 1,179,648
  const size_t o_bqkv = o_Wft + 1179648;          // 32,768
  const size_t o_prt  = o_bqkv + 32768;           // 8,192 (Wo partials, 192)
  const size_t o_mn   = o_prt + 8192;             // 256
  const size_t o_bff  = o_mn + 256;               // 4,096 (adjusted FF bias)
  const size_t o_cs   = o_bff + 4096;             // 4,096 (colsum Wf)
  const size_t o_part = o_cs + 4096;              // 12*8*2048*8 = 1,572,864
  const size_t o_xb   = o_part + 1572864;         // 12,582,912
  const size_t o_Q    = o_xb + 12582912;
  const size_t o_K    = o_Q + MSZ;
  const size_t o_Vt   = o_K + MSZ;
  const size_t o_P    = o_Vt + MSZ;               // 56,623,104
  const size_t o_end  = o_P + 56623104;           // ~199.4 MB
  if (ws_size < o_end) return;

  const size_t o_O  = o_Q;   // Q dead after scores
  const size_t o_yb = o_xb;  // xb dead after QKV

  OffN z0{};
  dim3 b32(32, 8);

  k_cast_x<<<6144, 256, 0, stream>>>(x, (u16*)(ws + o_xb));
  k_wt3<<<dim3(72, 24, 3), b32, 0, stream>>>(Wq, Wk, Wv, (u16*)(ws + o_Wqkvt));
  k_wt<<<dim3(24, 72), b32, 0, stream>>>(Wo, (u16*)(ws + o_Wot), 2304, 768);
  k_wt<<<dim3(24, 24), b32, 0, stream>>>(Wf, (u16*)(ws + o_Wft), 768, 768);
  k_bias_concat<<<27, 256, 0, stream>>>(bq, bk, bv, (float*)(ws + o_bqkv));
  k_colsum<<<12, 256, 0, stream>>>(Wf, (float*)(ws + o_cs));   // early, parallel

  k_qkv256<<<dim3(27, 32), 512, 0, stream>>>(
      (const u16*)(ws + o_xb), (const u16*)(ws + o_Wqkvt),
      (const float*)(ws + o_bqkv), (u16*)(ws + o_Q), (u16*)(ws + o_Vt));

  // single-chunk attention: all 12 heads; rescale fused into PV
  OffN so{}, po{};
  for (int zz = 0; zz < 12; zz++) {
    const int b = zz / 3, h = zz % 3;
    so.a[zz] = (size_t)b * 2048 * 2304 + (size_t)h * 768;   // Q (u16)
    so.b[zz] = so.a[zz];                                     // K (u16)
    so.c[zz] = (size_t)zz * 2359296;                         // P (u16)
    po.a[zz] = so.c[zz];                                     // P (u16)
    po.b[zz] = (size_t)zz * 768 * 2048;                      // Vt (u16)
    po.c[zz] = so.a[zz];                                     // O (u16)
  }
  k_g128<G128_SC><<<dim3(8, 16, 12), 512, 0, stream>>>(
      (const u16*)(ws + o_Q), (const u16*)(ws + o_K), nullptr, ws + o_P,
      (float*)(ws + o_part), nullptr, 2304, 2304, 0, 768, so);
  k_g128<G128_PV><<<dim3(36, 16), 512, 0, stream>>>(
      (const u16*)(ws + o_P), (const u16*)(ws + o_Vt), nullptr, ws + o_O,
      (float*)(ws + o_part), nullptr, 0, 2048, 0, 0, po);

  // Wo fused: yb = bf16(bf16(a) + x) coalesced, partial sums of a -> o_prt
  k_g128<G128_WO><<<dim3(3, 64), 512, 0, stream>>>(
      (const u16*)(ws + o_O), (const u16*)(ws + o_Wot), bo, ws + o_yb,
      (float*)(ws + o_prt), x, 2304, 2304, 768, 2304, z0);

  k_mean<<<1, 256, 0, stream>>>((const float*)(ws + o_prt), (float*)(ws + o_mn));
  k_ffbias<<<3, 256, 0, stream>>>((const float*)(ws + o_cs), bfb,
                                  (const float*)(ws + o_mn), (float*)(ws + o_bff));

  k_g128<G128_LEAKY><<<dim3(3, 64), 512, 0, stream>>>(
      (const u16*)(ws + o_yb), (const u16*)(ws + o_Wft),
      (const float*)(ws + o_bff), d_out,
      nullptr, nullptr, 768, 768, 768, 768, z0);
}